// Round 2
// baseline (382.730 us; speedup 1.0000x reference)
//
#include <hip/hip_runtime.h>

typedef short s16x8 __attribute__((ext_vector_type(8)));
typedef float f32x4 __attribute__((ext_vector_type(4)));

#define N_SAMPLES 65536
#define DIM 768
#define HID 384
#define NEXP 8
#define NCLS 8

// workspace layout (bytes)
#define WS_CNT    0
#define WS_BUCKET 1024
#define WS_W1T    (WS_BUCKET + NEXP * N_SAMPLES * 4)   // 2,098,176
#define WS_W2T    (WS_W1T + NEXP * HID * DIM * 2)      // 6,816,768
// total ~6.87 MB

__device__ __forceinline__ unsigned short f2bf(float f) {
  union { float f; unsigned u; } v; v.f = f;
  unsigned r = v.u + 0x7fffu + ((v.u >> 16) & 1u);   // RNE, finite inputs
  return (unsigned short)(r >> 16);
}

// W1[e][k=768][j=384] f32 -> W1T[e][j=384][k=768] bf16 ; block(0,0,0) zeroes cnt
__global__ void k_transpose_w1(const float* __restrict__ W1,
                               unsigned short* __restrict__ W1T,
                               int* __restrict__ cnt) {
  if (blockIdx.x == 0 && blockIdx.y == 0 && blockIdx.z == 0 &&
      threadIdx.y == 0 && threadIdx.x < NEXP)
    cnt[threadIdx.x] = 0;
  __shared__ float tile[32][33];
  const int e = blockIdx.z, k0 = blockIdx.x * 32, j0 = blockIdx.y * 32;
  const int tx = threadIdx.x, ty = threadIdx.y;
  const float* src = W1 + (size_t)e * DIM * HID;
#pragma unroll
  for (int i = 0; i < 32; i += 8)
    tile[ty + i][tx] = src[(size_t)(k0 + ty + i) * HID + j0 + tx];
  __syncthreads();
  unsigned short* dst = W1T + (size_t)e * HID * DIM;
#pragma unroll
  for (int i = 0; i < 32; i += 8)
    dst[(size_t)(j0 + ty + i) * DIM + k0 + tx] = f2bf(tile[tx][ty + i]);
}

// blocks 0..255: bucket rows by expert + out[i][:] = b2[qt[i]][:]
// blocks 256..263: W2[e] f32 -> W2T[e][c=8][j=384] bf16
__global__ void k_scatter_init(const int* __restrict__ qt, const float* __restrict__ b2,
                               const float* __restrict__ W2,
                               int* __restrict__ cnt, int* __restrict__ bucket,
                               float* __restrict__ out, unsigned short* __restrict__ W2T) {
  const int t = threadIdx.x;
  if (blockIdx.x >= 256) {
    const int e = blockIdx.x - 256;
    for (int j = t; j < HID; j += 256)
#pragma unroll
      for (int c = 0; c < NCLS; ++c)
        W2T[((size_t)e * NCLS + c) * HID + j] =
            f2bf(W2[((size_t)e * HID + j) * NCLS + c]);
    return;
  }
  __shared__ int lcnt[NEXP], lbase[NEXP];
  const int i = blockIdx.x * 256 + t;
  if (t < NEXP) lcnt[t] = 0;
  __syncthreads();
  const int e = qt[i];
  const int rank = atomicAdd(&lcnt[e], 1);
  __syncthreads();
  if (t < NEXP) lbase[t] = atomicAdd(&cnt[t], lcnt[t]);
  __syncthreads();
  bucket[(size_t)e * N_SAMPLES + lbase[e] + rank] = i;
  const float4* b2v = (const float4*)(b2 + e * NCLS);
  float4* ov = (float4*)(out + (size_t)i * NCLS);
  ov[0] = b2v[0];
  ov[1] = b2v[1];
}

#define GLL16(g, l)                                                        \
  __builtin_amdgcn_global_load_lds(                                        \
      (__attribute__((address_space(1))) void*)(void*)(g),                 \
      (__attribute__((address_space(3))) void*)(l), 16, 0, 0)

// One K-step: compute on (AC,BC); prefetch next B into BN (GLL after barrier)
// and next A chunk into v0..v3. Single barrier per step; every vmem op has a
// full compute phase in flight before the barrier that drains it.
#define K_STEP(KS, AC, BC, BN)                                                  \
  {                                                                             \
    s16x8 p0 = {(short)f2bf(v0.x), (short)f2bf(v0.y), (short)f2bf(v0.z),        \
                (short)f2bf(v0.w), (short)f2bf(v1.x), (short)f2bf(v1.y),        \
                (short)f2bf(v1.z), (short)f2bf(v1.w)};                          \
    s16x8 p1 = {(short)f2bf(v2.x), (short)f2bf(v2.y), (short)f2bf(v2.z),        \
                (short)f2bf(v2.w), (short)f2bf(v3.x), (short)f2bf(v3.y),        \
                (short)f2bf(v3.z), (short)f2bf(v3.w)};                          \
    *(s16x8*)&(AC)[t * 16] = p0;                                                \
    *(s16x8*)&(AC)[t * 16 + 8] = p1;                                            \
    __syncthreads();                                                            \
    if ((KS) + 1 < 24) {                                                        \
      GLL16(g0 + ((KS) + 1) * 32, &(BN)[t * 8]);                                \
      GLL16(g1 + ((KS) + 1) * 32, &(BN)[2048 + t * 8]);                         \
      const float4* nx = (const float4*)(xrow + ((KS) + 1) * 32);               \
      v0 = nx[0]; v1 = nx[1]; v2 = nx[2]; v3 = nx[3];                           \
    }                                                                           \
    s16x8 bfr[4];                                                               \
    _Pragma("unroll")                                                           \
    for (int ni = 0; ni < 4; ++ni)                                              \
      bfr[ni] = *(const s16x8*)&(BC)[(nbase + ni * 16 + lrow) * 32 + lk];       \
    _Pragma("unroll")                                                           \
    for (int mi = 0; mi < 4; ++mi) {                                            \
      s16x8 afr = *(const s16x8*)&(AC)[(mbase + mi * 16 + lrow) * 32 + lk];     \
      _Pragma("unroll")                                                         \
      for (int ni = 0; ni < 4; ++ni)                                            \
        acc[mi][ni] = __builtin_amdgcn_mfma_f32_16x16x32_bf16(                  \
            afr, bfr[ni], acc[mi][ni], 0, 0, 0);                                \
    }                                                                           \
  }

// grouped gather-GEMM: per block = (expert e, 128 gathered rows, 128 of 384 H)
__global__ __launch_bounds__(256, 3) void k_moe_gemm(
    const float* __restrict__ x, const unsigned short* __restrict__ W1T,
    const float* __restrict__ b1, const unsigned short* __restrict__ W2T,
    const int* __restrict__ cnt, const int* __restrict__ bucket,
    float* __restrict__ out) {
  // smem: K-loop uses 4 x 8KB staging buffers (A dbuf + B dbuf); epilogue Hs
  // (128 x 136 bf16 = 34816 B) aliases all of them (safe: barrier-separated).
  __shared__ __align__(16) short smem[17408];
  __shared__ __align__(16) short W2s[16 * 128];
  __shared__ float b1s[128];
  __shared__ int idxs[128];
  short* As0 = smem;           // [128 m][32 k] bf16
  short* As1 = smem + 4096;
  short* Bs0 = smem + 8192;    // [128 j][32 k] bf16
  short* Bs1 = smem + 12288;
  short* Hs = smem;            // [128 m][136 j] bf16

  const int e = blockIdx.z;
  const int n_e = cnt[e];
  const int j0 = blockIdx.x * 128;           // h-tile base (0,128,256)
  const int t = threadIdx.x;
  const int lane = t & 63;
  const int wave = t >> 6;
  const int lrow = lane & 15;
  const int quad = lane >> 4;
  const int lk = quad * 8;
  const int mbase = (wave & 1) * 64;
  const int nbase = (wave >> 1) * 64;

  // per-block persistent preloads (independent of row tile)
  {
    const int c = t >> 4, jj = (t & 15) * 8;
    s16x8 wv = {0, 0, 0, 0, 0, 0, 0, 0};
    if (c < NCLS) wv = *(const s16x8*)&W2T[((size_t)e * NCLS + c) * HID + j0 + jj];
    *(s16x8*)&W2s[c * 128 + jj] = wv;       // [c(16, zero-padded)][j(128)]
  }
  if (t < 128) b1s[t] = b1[e * HID + j0 + t];

  for (int rt = blockIdx.y; rt * 128 < n_e; rt += gridDim.y) {
    const int row0 = rt * 128;
    __syncthreads();   // prev epilogue-2 LDS reads done / first-iter preloads done
    if (t < 128) {
      const int slot = row0 + t;
      idxs[t] = bucket[(size_t)e * N_SAMPLES + ((slot < n_e) ? slot : row0)];
    }
    __syncthreads();

    // A staging map: thread t -> row t>>1, k-half (t&1)*16 floats
    const float* xrow = x + (size_t)idxs[t >> 1] * DIM + (t & 1) * 16;
    // B staging map: 16B unit per thread: j = (t>>2) [+64], k = (t&3)*8
    const unsigned short* g0 = W1T + ((size_t)(e * HID + j0 + (t >> 2)) * DIM + (t & 3) * 8);
    const unsigned short* g1 = W1T + ((size_t)(e * HID + j0 + 64 + (t >> 2)) * DIM + (t & 3) * 8);

    f32x4 acc[4][4];
#pragma unroll
    for (int mi = 0; mi < 4; ++mi)
#pragma unroll
      for (int ni = 0; ni < 4; ++ni) acc[mi][ni] = (f32x4){0.f, 0.f, 0.f, 0.f};

    // preissue for ks=0 (exposed once per row tile; amortized over 24 steps)
    float4 v0 = ((const float4*)xrow)[0];
    float4 v1 = ((const float4*)xrow)[1];
    float4 v2 = ((const float4*)xrow)[2];
    float4 v3 = ((const float4*)xrow)[3];
    GLL16(g0, &Bs0[t * 8]);
    GLL16(g1, &Bs0[2048 + t * 8]);

    for (int ks = 0; ks < 24; ks += 2) {
      K_STEP(ks, As0, Bs0, Bs1)
      K_STEP(ks + 1, As1, Bs1, Bs0)
    }

    __syncthreads();   // all K-loop LDS reads done before Hs overwrite

    // epilogue 1: bias + relu, C-layout (col=lane&15, row=quad*4+r) -> Hs bf16
#pragma unroll
    for (int ni = 0; ni < 4; ++ni) {
      const int jl = nbase + ni * 16 + lrow;
      const float bias = b1s[jl];
#pragma unroll
      for (int mi = 0; mi < 4; ++mi) {
        const int mrow = mbase + mi * 16 + quad * 4;
#pragma unroll
        for (int r = 0; r < 4; ++r) {
          float v = acc[mi][ni][r] + bias;
          v = v > 0.f ? v : 0.f;
          Hs[(mrow + r) * 136 + jl] = (short)f2bf(v);
        }
      }
    }
    __syncthreads();

    // epilogue 2: layer-2 MFMA (M=128 over 8 m-tiles, N=16 (8 valid), K=128)
#pragma unroll
    for (int p = 0; p < 2; ++p) {
      const int mt = wave * 2 + p;
      f32x4 acc2 = (f32x4){0.f, 0.f, 0.f, 0.f};
#pragma unroll
      for (int kk = 0; kk < 4; ++kk) {
        s16x8 af = *(const s16x8*)&Hs[(mt * 16 + lrow) * 136 + kk * 32 + lk];
        s16x8 bf = *(const s16x8*)&W2s[lrow * 128 + kk * 32 + lk];
        acc2 = __builtin_amdgcn_mfma_f32_16x16x32_bf16(af, bf, acc2, 0, 0, 0);
      }
      if (lrow < NCLS) {
#pragma unroll
        for (int r = 0; r < 4; ++r) {
          const int m = mt * 16 + quad * 4 + r;
          if (row0 + m < n_e)
            atomicAdd(out + (size_t)idxs[m] * NCLS + lrow, acc2[r]);
        }
      }
    }
  }
}

extern "C" void kernel_launch(void* const* d_in, const int* in_sizes, int n_in,
                              void* d_out, int out_size, void* d_ws, size_t ws_size,
                              hipStream_t stream) {
  const float* x  = (const float*)d_in[0];
  const float* W1 = (const float*)d_in[1];
  const float* b1 = (const float*)d_in[2];
  const float* W2 = (const float*)d_in[3];
  const float* b2 = (const float*)d_in[4];
  const int* qt   = (const int*)d_in[5];
  float* out = (float*)d_out;
  char* ws = (char*)d_ws;

  int* cnt = (int*)(ws + WS_CNT);
  int* bucket = (int*)(ws + WS_BUCKET);
  unsigned short* W1T = (unsigned short*)(ws + WS_W1T);
  unsigned short* W2T = (unsigned short*)(ws + WS_W2T);

  k_transpose_w1<<<dim3(24, 12, 8), dim3(32, 8), 0, stream>>>(W1, W1T, cnt);
  k_scatter_init<<<dim3(264), dim3(256), 0, stream>>>(qt, b2, W2, cnt, bucket, out, W2T);
  k_moe_gemm<<<dim3(3, 32, 8), dim3(256), 0, stream>>>(x, W1T, b1, W2T, cnt, bucket, out);
}

// Round 3
// 349.112 us; speedup vs baseline: 1.0963x; 1.0963x over previous
//
#include <hip/hip_runtime.h>

typedef short s16x8 __attribute__((ext_vector_type(8)));
typedef float f32x4 __attribute__((ext_vector_type(4)));

#define N_SAMPLES 65536
#define DIM 768
#define HID 384
#define NEXP 8
#define NCLS 8

// workspace layout (bytes)
#define WS_CNT    0
#define WS_BUCKET 1024
#define WS_W1T    (WS_BUCKET + NEXP * N_SAMPLES * 4)   // 2,098,176
// total = WS_W1T + 8*384*768*2 = 6,816,768 (~6.8 MB)

// RNE bf16 (prep kernels only — off the hot path)
__device__ __forceinline__ unsigned short f2bf(float f) {
  union { float f; unsigned u; } v; v.f = f;
  unsigned r = v.u + 0x7fffu + ((v.u >> 16) & 1u);
  return (unsigned short)(r >> 16);
}

// fast half-up scalar (2 VALU)
__device__ __forceinline__ short f2bf_fast(float f) {
  union { float f; unsigned u; } v; v.f = f;
  return (short)((v.u + 0x8000u) >> 16);
}

// fast half-up pair: 2x v_add + 1x v_perm = 1.5 VALU/element.
// result: low16 = bf(a), high16 = bf(b)  (memory order [a,b] little-endian)
__device__ __forceinline__ unsigned cvt2(float a, float b) {
  union { float f; unsigned u; } ua, ub;
  ua.f = a; ub.f = b;
  // v_perm_b32 pool: bytes 0-3 = S1, bytes 4-7 = S0; take hi16 of each
  return __builtin_amdgcn_perm(ub.u + 0x8000u, ua.u + 0x8000u, 0x07060302u);
}

// W1[e][k=768][j=384] f32 -> W1T[e][j=384][k=768] bf16 ; block(0,0,0) zeroes cnt
__global__ void k_transpose_w1(const float* __restrict__ W1,
                               unsigned short* __restrict__ W1T,
                               int* __restrict__ cnt) {
  if (blockIdx.x == 0 && blockIdx.y == 0 && blockIdx.z == 0 &&
      threadIdx.y == 0 && threadIdx.x < NEXP)
    cnt[threadIdx.x] = 0;
  __shared__ float tile[32][33];
  const int e = blockIdx.z, k0 = blockIdx.x * 32, j0 = blockIdx.y * 32;
  const int tx = threadIdx.x, ty = threadIdx.y;
  const float* src = W1 + (size_t)e * DIM * HID;
#pragma unroll
  for (int i = 0; i < 32; i += 8)
    tile[ty + i][tx] = src[(size_t)(k0 + ty + i) * HID + j0 + tx];
  __syncthreads();
  unsigned short* dst = W1T + (size_t)e * HID * DIM;
#pragma unroll
  for (int i = 0; i < 32; i += 8)
    dst[(size_t)(j0 + ty + i) * DIM + k0 + tx] = f2bf(tile[tx][ty + i]);
}

// bucket rows by expert (block-local LDS histogram -> 1 global atomic/expert/block)
__global__ void k_scatter(const int* __restrict__ qt, int* __restrict__ cnt,
                          int* __restrict__ bucket) {
  __shared__ int lcnt[NEXP], lbase[NEXP];
  const int t = threadIdx.x;
  const int i = blockIdx.x * 256 + t;
  if (t < NEXP) lcnt[t] = 0;
  __syncthreads();
  const int e = qt[i];
  const int rank = atomicAdd(&lcnt[e], 1);
  __syncthreads();
  if (t < NEXP) lbase[t] = atomicAdd(&cnt[t], lcnt[t]);
  __syncthreads();
  bucket[(size_t)e * N_SAMPLES + lbase[e] + rank] = i;
}

#define GLL16(g, l)                                                        \
  __builtin_amdgcn_global_load_lds(                                        \
      (__attribute__((address_space(1))) void*)(void*)(g),                 \
      (__attribute__((address_space(3))) void*)(l), 16, 0, 0)

// stage full B k-slice (384 j x 32 k bf16 = 24KB) for step KS into BUF
#define GLLB(KS, BUF)                                                      \
  _Pragma("unroll") for (int rep = 0; rep < 6; ++rep)                      \
      GLL16(bp + (size_t)rep * 64 * DIM + (KS) * 32, &(BUF)[(rep * 256 + t) * 8]);

// convert 8 staged floats -> one ds_write_b128 into A tile (stride 40 shorts)
#define ASTORE(BUF, LO, HI)                                                \
  {                                                                        \
    unsigned p01 = cvt2((LO).x, (LO).y), p23 = cvt2((LO).z, (LO).w);       \
    unsigned p45 = cvt2((HI).x, (HI).y), p67 = cvt2((HI).z, (HI).w);       \
    uint4 pk = {p01, p23, p45, p67};                                       \
    *(uint4*)&(BUF)[ar * 40 + aq * 8] = pk;                                \
  }

#define COMPUTE(AS, BS)                                                    \
  {                                                                        \
    s16x8 bfr[6];                                                          \
    _Pragma("unroll") for (int ni = 0; ni < 6; ++ni)                       \
        bfr[ni] = *(const s16x8*)&(BS)[(wave * 96 + ni * 16 + lrow) * 32 + quad * 8]; \
    _Pragma("unroll") for (int mi = 0; mi < 4; ++mi) {                     \
      s16x8 afr = *(const s16x8*)&(AS)[(mi * 16 + lrow) * 40 + quad * 8];  \
      _Pragma("unroll") for (int ni = 0; ni < 6; ++ni)                     \
          acc[mi][ni] = __builtin_amdgcn_mfma_f32_16x16x32_bf16(           \
              afr, bfr[ni], acc[mi][ni], 0, 0, 0);                         \
    }                                                                      \
  }

// grouped gather-GEMM: block = (expert e = blockIdx.x -> pinned XCD, 64 rows, all 384 H)
// h = relu(x@W1[e]+b1); out[rows] = h@W2[e]+b2  (complete rows, no atomics)
__global__ __launch_bounds__(256, 2) void k_moe_gemm(
    const float* __restrict__ x, const unsigned short* __restrict__ W1T,
    const float* __restrict__ b1, const float* __restrict__ W2,
    const float* __restrict__ b2, const int* __restrict__ cnt,
    const int* __restrict__ bucket, float* __restrict__ out) {
  // staging: As dbuf 2x(64x40) + Bs dbuf 2x(384x32) = 29696 shorts (59392 B)
  // epilogue Hs (64x392 = 25088 shorts) aliases it (barrier-separated).
  __shared__ __align__(16) short smem[29696];
  __shared__ __align__(16) short W2s[16 * 392];   // rows c (8 valid + 8 zero)
  __shared__ float b1s[HID];
  __shared__ float b2s[NCLS];
  short* As0 = smem;            // [64 m][40 k-pad] bf16
  short* As1 = smem + 2560;
  short* Bs0 = smem + 5120;     // [384 j][32 k] bf16
  short* Bs1 = smem + 17408;
  short* Hs  = smem;            // [64 m][392 j] bf16

  const int e = blockIdx.x;
  const int n_e = cnt[e];
  const int t = threadIdx.x;
  const int lane = t & 63;
  const int wave = t >> 6;
  const int lrow = lane & 15;
  const int quad = lane >> 4;
  const int ar = t >> 2;        // A staging row (0..63)
  const int aq = t & 3;         // A staging k-chunk (8 floats)

  // per-block preloads (expert-wide, reused across row tiles)
  for (int j = t; j < HID; j += 256) {
    b1s[j] = b1[e * HID + j];
    const float* wr = W2 + ((size_t)e * HID + j) * NCLS;
#pragma unroll
    for (int c = 0; c < NCLS; ++c) W2s[c * 392 + j] = (short)f2bf(wr[c]);
#pragma unroll
    for (int c = NCLS; c < 16; ++c) W2s[c * 392 + j] = 0;
  }
  if (t < NCLS) b2s[t] = b2[e * NCLS + t];

  const unsigned short* bp = W1T + ((size_t)e * HID + (t >> 2)) * DIM + (t & 3) * 8;

  for (int rt = blockIdx.y; rt * 64 < n_e; rt += gridDim.y) {
    const int row0 = rt * 64;
    int slot = row0 + ar;
    if (slot >= n_e) slot = n_e - 1;                 // clamp: dup compute, masked store
    const int aidx = bucket[(size_t)e * N_SAMPLES + slot];
    const float* ap = x + (size_t)aidx * DIM + aq * 8;

    f32x4 acc[4][6];
#pragma unroll
    for (int mi = 0; mi < 4; ++mi)
#pragma unroll
      for (int ni = 0; ni < 6; ++ni) acc[mi][ni] = (f32x4){0.f, 0.f, 0.f, 0.f};

    // pipeline fill: ks=0 fully staged, ks=1 A-regs in flight
    float4 a0lo = ((const float4*)ap)[0];
    float4 a0hi = ((const float4*)(ap + 4))[0];
    GLLB(0, Bs0)
    ASTORE(As0, a0lo, a0hi)
    float4 a1lo = ((const float4*)(ap + 32))[0];
    float4 a1hi = ((const float4*)(ap + 36))[0];

    for (int ks = 0; ks < 24; ks += 2) {
      __syncthreads();   // drains: GLL Bs[ks&1], As[ks&1] writes, A-regs(ks+1)
      if (ks + 1 < 24) { GLLB(ks + 1, Bs1) ASTORE(As1, a1lo, a1hi) }
      if (ks + 2 < 24) {
        a0lo = ((const float4*)(ap + (ks + 2) * 32))[0];
        a0hi = ((const float4*)(ap + (ks + 2) * 32 + 4))[0];
      }
      COMPUTE(As0, Bs0)
      __syncthreads();
      if (ks + 2 < 24) { GLLB(ks + 2, Bs0) ASTORE(As0, a0lo, a0hi) }
      if (ks + 3 < 24) {
        a1lo = ((const float4*)(ap + (ks + 3) * 32))[0];
        a1hi = ((const float4*)(ap + (ks + 3) * 32 + 4))[0];
      }
      COMPUTE(As1, Bs1)
    }

    __syncthreads();   // all K-loop LDS reads done before Hs overwrite

    // epilogue 1: bias + relu -> Hs bf16 (C layout: col=lane&15, row=quad*4+r)
#pragma unroll
    for (int mi = 0; mi < 4; ++mi)
#pragma unroll
      for (int ni = 0; ni < 6; ++ni) {
        const int j = wave * 96 + ni * 16 + lrow;
        const float bias = b1s[j];
#pragma unroll
        for (int r = 0; r < 4; ++r) {
          float v = acc[mi][ni][r] + bias;
          v = v > 0.f ? v : 0.f;
          Hs[(mi * 16 + quad * 4 + r) * 392 + j] = f2bf_fast(v);
        }
      }
    __syncthreads();

    // epilogue 2: layer-2 MFMA, M=64 (m-tile = wave), N=16 (8 valid), K=384
    {
      f32x4 acc2 = (f32x4){0.f, 0.f, 0.f, 0.f};
#pragma unroll
      for (int kk = 0; kk < 12; ++kk) {
        s16x8 af = *(const s16x8*)&Hs[(wave * 16 + lrow) * 392 + kk * 32 + quad * 8];
        s16x8 bf = *(const s16x8*)&W2s[lrow * 392 + kk * 32 + quad * 8];
        acc2 = __builtin_amdgcn_mfma_f32_16x16x32_bf16(af, bf, acc2, 0, 0, 0);
      }
      if (lrow < NCLS) {
        const float bb = b2s[lrow];
#pragma unroll
        for (int r = 0; r < 4; ++r) {
          const int m = wave * 16 + quad * 4 + r;
          if (row0 + m < n_e) {
            const int oi = bucket[(size_t)e * N_SAMPLES + row0 + m];
            out[(size_t)oi * NCLS + lrow] = acc2[r] + bb;
          }
        }
      }
    }
    __syncthreads();   // Hs reads done before next tile's staging writes
  }
}

extern "C" void kernel_launch(void* const* d_in, const int* in_sizes, int n_in,
                              void* d_out, int out_size, void* d_ws, size_t ws_size,
                              hipStream_t stream) {
  const float* x  = (const float*)d_in[0];
  const float* W1 = (const float*)d_in[1];
  const float* b1 = (const float*)d_in[2];
  const float* W2 = (const float*)d_in[3];
  const float* b2 = (const float*)d_in[4];
  const int* qt   = (const int*)d_in[5];
  float* out = (float*)d_out;
  char* ws = (char*)d_ws;

  int* cnt = (int*)(ws + WS_CNT);
  int* bucket = (int*)(ws + WS_BUCKET);
  unsigned short* W1T = (unsigned short*)(ws + WS_W1T);

  k_transpose_w1<<<dim3(24, 12, 8), dim3(32, 8), 0, stream>>>(W1, W1T, cnt);
  k_scatter<<<dim3(256), dim3(256), 0, stream>>>(qt, cnt, bucket);
  k_moe_gemm<<<dim3(8, 64), dim3(256), 0, stream>>>(x, W1T, b1, W2, b2, cnt, bucket, out);
}

// Round 4
// 334.820 us; speedup vs baseline: 1.1431x; 1.0427x over previous
//
#include <hip/hip_runtime.h>

typedef short s16x8 __attribute__((ext_vector_type(8)));
typedef float f32x4 __attribute__((ext_vector_type(4)));

#define N_SAMPLES 65536
#define DIM 768
#define HID 384
#define NEXP 8
#define NCLS 8
#define JT 24   // HID/16
#define KT 24   // DIM/32

// workspace layout (bytes)
#define WS_CNT    0
#define WS_BUCKET 1024
#define WS_W1F    (WS_BUCKET + NEXP * N_SAMPLES * 4)   // 2,098,176
// W1F = 8*24*24*64*8 shorts = 4,718,592 B -> total 6,816,768

// RNE bf16 (prep only)
__device__ __forceinline__ unsigned short f2bf(float f) {
  union { float f; unsigned u; } v; v.f = f;
  unsigned r = v.u + 0x7fffu + ((v.u >> 16) & 1u);
  return (unsigned short)(r >> 16);
}

// fast half-up pair: 2x v_add + 1x v_perm = 1.5 VALU/element
// result: low16 = bf(a), high16 = bf(b)
__device__ __forceinline__ unsigned cvt2(float a, float b) {
  union { float f; unsigned u; } ua, ub;
  ua.f = a; ub.f = b;
  return __builtin_amdgcn_perm(ub.u + 0x8000u, ua.u + 0x8000u, 0x07060302u);
}

// lgkm-only barrier (CK block_sync_lds): does NOT drain vmcnt, so global
// register prefetches stay in flight across it.
#define LBAR asm volatile("s_waitcnt lgkmcnt(0)\n\ts_barrier" ::: "memory")

// W1[e][k=768][j=384] f32 -> W1F in MFMA A-fragment order:
// W1F[((e*JT+jt)*KT+kt)*64 + lane][i] = W1[e][kt*32+(lane>>4)*8+i][jt*16+(lane&15)]
__global__ void k_w1frag(const float* __restrict__ W1,
                         unsigned short* __restrict__ W1F,
                         int* __restrict__ cnt) {
  if (blockIdx.x == 0 && blockIdx.y == 0 && threadIdx.x < NEXP)
    cnt[threadIdx.x] = 0;
  const int e = blockIdx.x;
  const int unit = blockIdx.y * 4 + (threadIdx.x >> 6);   // (jt,kt) flat, 0..575
  const int lane = threadIdx.x & 63;
  const int jt = unit / KT, kt = unit % KT;
  const int j = jt * 16 + (lane & 15);
  const int k0 = kt * 32 + (lane >> 4) * 8;
  const float* src = W1 + ((size_t)e * DIM + k0) * HID + j;
  s16x8 v;
#pragma unroll
  for (int i = 0; i < 8; ++i) v[i] = (short)f2bf(src[(size_t)i * HID]);
  *(s16x8*)&W1F[(((size_t)e * JT * KT + unit) * 64 + lane) * 8] = v;
}

// bucket rows by expert
__global__ void k_scatter(const int* __restrict__ qt, int* __restrict__ cnt,
                          int* __restrict__ bucket) {
  __shared__ int lcnt[NEXP], lbase[NEXP];
  const int t = threadIdx.x;
  const int i = blockIdx.x * 256 + t;
  if (t < NEXP) lcnt[t] = 0;
  __syncthreads();
  const int e = qt[i];
  const int rank = atomicAdd(&lcnt[e], 1);
  __syncthreads();
  if (t < NEXP) lbase[t] = atomicAdd(&cnt[t], lcnt[t]);
  __syncthreads();
  bucket[(size_t)e * N_SAMPLES + lbase[e] + rank] = i;
}

// load 8 floats of this thread's x row for k-step KS
#define ALOAD(LO, HI, KS)                                   \
  { const float4* p_ = (const float4*)(ap + (KS) * 32);     \
    LO = p_[0]; HI = p_[1]; }

// cvt 8 floats -> 16B ds_write_b128 into A tile ([64][40] bf16)
#define ASTORE(BUF, LO, HI)                                               \
  { unsigned q0 = cvt2((LO).x, (LO).y), q1 = cvt2((LO).z, (LO).w);        \
    unsigned q2 = cvt2((HI).x, (HI).y), q3 = cvt2((HI).z, (HI).w);        \
    uint4 pk_ = {q0, q1, q2, q3};                                         \
    *(uint4*)&(BUF)[ar * 40 + aq * 8] = pk_; }

// 6 coalesced b128 fragment loads of W1F for k-step KS (from L2)
#define WLOAD(DST, KS)                                                    \
  _Pragma("unroll") for (int ni = 0; ni < 6; ++ni)                        \
      DST[ni] = *(const s16x8*)(wfbase + ((size_t)ni * KT + (KS)) * 512);

// 4 ds_read_b128 (x frags, 2-way free) + 24 MFMA; wf = A-operand (j), x = B (m)
#define COMPUTE(AS, WF)                                                   \
  { _Pragma("unroll") for (int mi = 0; mi < 4; ++mi) {                    \
      s16x8 xfr = *(const s16x8*)&(AS)[(mi * 16 + lrow) * 40 + quad * 8]; \
      _Pragma("unroll") for (int ni = 0; ni < 6; ++ni)                    \
          acc[mi][ni] = __builtin_amdgcn_mfma_f32_16x16x32_bf16(          \
              WF[ni], xfr, acc[mi][ni], 0, 0, 0); } }

// block = (expert e -> pinned XCD, 64 gathered rows, all 384 H)
__global__ __launch_bounds__(256, 2) void k_moe_gemm(
    const float* __restrict__ x, const unsigned short* __restrict__ W1F,
    const float* __restrict__ b1, const float* __restrict__ W2,
    const float* __restrict__ b2, const int* __restrict__ cnt,
    const int* __restrict__ bucket, float* __restrict__ out) {
  // Hs (64x392 bf16 = 50 KB) overlays the two tiny A staging buffers.
  __shared__ __align__(16) short smem[25088];
  __shared__ __align__(16) short W2s[16 * 392];
  __shared__ float b1s[HID];
  __shared__ float b2s[NCLS];
  short* As0 = smem;            // [64 m][40 k-pad] bf16
  short* As1 = smem + 2560;
  short* Hs  = smem;            // [64 m][392 j] bf16

  const int e = blockIdx.x;
  const int n_e = cnt[e];
  const int t = threadIdx.x;
  const int lane = t & 63;
  const int wave = t >> 6;
  const int lrow = lane & 15;
  const int quad = lane >> 4;
  const int ar = t >> 2;        // A staging row (0..63)
  const int aq = t & 3;         // A staging k-chunk (8 floats)

  for (int j = t; j < HID; j += 256) {
    b1s[j] = b1[e * HID + j];
    const float* wr = W2 + ((size_t)e * HID + j) * NCLS;
#pragma unroll
    for (int c = 0; c < NCLS; ++c) W2s[c * 392 + j] = (short)f2bf(wr[c]);
#pragma unroll
    for (int c = NCLS; c < 16; ++c) W2s[c * 392 + j] = 0;
  }
  if (t < NCLS) b2s[t] = b2[e * NCLS + t];

  // this wave's W1F base: jt = wave*6 + ni, per-kt stride 512 shorts
  const unsigned short* wfbase =
      W1F + ((size_t)(e * JT + wave * 6) * KT) * 512 + lane * 8;

  for (int rt = blockIdx.y; rt * 64 < n_e; rt += gridDim.y) {
    const int row0 = rt * 64;
    int slot = row0 + ar;
    if (slot >= n_e) slot = n_e - 1;            // clamp: dup compute, masked store
    const int aidx = bucket[(size_t)e * N_SAMPLES + slot];
    const float* ap = x + (size_t)aidx * DIM + aq * 8;

    f32x4 acc[4][6];
#pragma unroll
    for (int mi = 0; mi < 4; ++mi)
#pragma unroll
      for (int ni = 0; ni < 6; ++ni) acc[mi][ni] = (f32x4){0.f, 0.f, 0.f, 0.f};

    float4 a0lo, a0hi, a1lo, a1hi;
    s16x8 wf0[6], wf1[6];
    ALOAD(a0lo, a0hi, 0)
    ASTORE(As0, a0lo, a0hi)
    ALOAD(a1lo, a1hi, 1)
    WLOAD(wf0, 0)
    LBAR;   // As0 visible; wf0/a1 stay in flight

    for (int ks = 0; ks < 24; ks += 2) {
      if (ks + 1 < 24) { ASTORE(As1, a1lo, a1hi) WLOAD(wf1, ks + 1) }
      if (ks + 2 < 24) ALOAD(a0lo, a0hi, ks + 2)
      COMPUTE(As0, wf0)
      LBAR;   // As1 visible; As0 reads done; prefetches NOT drained
      if (ks + 2 < 24) { ASTORE(As0, a0lo, a0hi) WLOAD(wf0, ks + 2) }
      if (ks + 3 < 24) ALOAD(a1lo, a1hi, ks + 3)
      COMPUTE(As1, wf1)
      LBAR;
    }

    // epilogue 1: bias+relu -> Hs[m][j]; acc: col(lane&15)=m, row(quad*4+r)=j
    // 4 consecutive j per lane -> one ds_write_b64 each (no scalar u16 writes)
#pragma unroll
    for (int mi = 0; mi < 4; ++mi)
#pragma unroll
      for (int ni = 0; ni < 6; ++ni) {
        const int j = wave * 96 + ni * 16 + quad * 4;
        const float4 bb = *(const float4*)&b1s[j];
        float v0 = acc[mi][ni][0] + bb.x; v0 = v0 > 0.f ? v0 : 0.f;
        float v1 = acc[mi][ni][1] + bb.y; v1 = v1 > 0.f ? v1 : 0.f;
        float v2 = acc[mi][ni][2] + bb.z; v2 = v2 > 0.f ? v2 : 0.f;
        float v3 = acc[mi][ni][3] + bb.w; v3 = v3 > 0.f ? v3 : 0.f;
        uint2 pk = {cvt2(v0, v1), cvt2(v2, v3)};
        *(uint2*)&Hs[(mi * 16 + lrow) * 392 + j] = pk;
      }
    LBAR;

    // epilogue 2: layer-2 MFMA, M=64 (m-tile = wave), N=16 (8 valid), K=384
    {
      f32x4 acc2 = (f32x4){0.f, 0.f, 0.f, 0.f};
#pragma unroll
      for (int kk = 0; kk < 12; ++kk) {
        s16x8 af = *(const s16x8*)&Hs[(wave * 16 + lrow) * 392 + kk * 32 + quad * 8];
        s16x8 bf = *(const s16x8*)&W2s[lrow * 392 + kk * 32 + quad * 8];
        acc2 = __builtin_amdgcn_mfma_f32_16x16x32_bf16(af, bf, acc2, 0, 0, 0);
      }
      if (lrow < NCLS) {
        const float bb = b2s[lrow];
#pragma unroll
        for (int r = 0; r < 4; ++r) {
          const int m = wave * 16 + quad * 4 + r;
          if (row0 + m < n_e) {
            const int oi = bucket[(size_t)e * N_SAMPLES + row0 + m];
            out[(size_t)oi * NCLS + lrow] = acc2[r] + bb;
          }
        }
      }
    }
    LBAR;   // Hs reads done before next tile's A staging
  }
}

extern "C" void kernel_launch(void* const* d_in, const int* in_sizes, int n_in,
                              void* d_out, int out_size, void* d_ws, size_t ws_size,
                              hipStream_t stream) {
  const float* x  = (const float*)d_in[0];
  const float* W1 = (const float*)d_in[1];
  const float* b1 = (const float*)d_in[2];
  const float* W2 = (const float*)d_in[3];
  const float* b2 = (const float*)d_in[4];
  const int* qt   = (const int*)d_in[5];
  float* out = (float*)d_out;
  char* ws = (char*)d_ws;

  int* cnt = (int*)(ws + WS_CNT);
  int* bucket = (int*)(ws + WS_BUCKET);
  unsigned short* W1F = (unsigned short*)(ws + WS_W1F);

  k_w1frag<<<dim3(8, 144), dim3(256), 0, stream>>>(W1, W1F, cnt);
  k_scatter<<<dim3(256), dim3(256), 0, stream>>>(qt, cnt, bucket);
  k_moe_gemm<<<dim3(8, 64), dim3(256), 0, stream>>>(x, W1F, b1, W2, b2, cnt, bucket, out);
}